// Round 4
// baseline (114.537 us; speedup 1.0000x reference)
//
#include <hip/hip_runtime.h>

#define B   2
#define C   256
#define CM  64     // compressed channels
#define CE  100    // encoder out channels
#define H   40
#define W   40
#define HW  1600
#define KK  25     // K*K

// ---------------------------------------------------------------------------
// K1: 1x1 conv 256 -> 64 as LDS GEMM, K(=x channels) split 4-way over blocks.
// grid (25 px-tiles, 4 K-quarters, 2 b), block 256 = 16 ty(oc) x 16 tx(px),
// thread tile 4 oc x 4 px. Output: fp32 partials pc[ich][b][64][1600].
// (unchanged from round 3)
// ---------------------------------------------------------------------------
__global__ __launch_bounds__(256) void k1_conv1x1(
    const float* __restrict__ x, const float* __restrict__ w,
    float* __restrict__ pc) {
  const int t = blockIdx.x, ich = blockIdx.y, b = blockIdx.z;
  __shared__ __align__(16) float xs[64 * 64];    // 16 KB [icl][px]
  __shared__ __align__(16) float wsA[64 * 64];   // 16 KB [icl][oc] (transposed)
  const int tid = threadIdx.x;

  const float4* x4 = (const float4*)(x + ((size_t)b * C + ich * 64) * HW + t * 64);
#pragma unroll
  for (int i = 0; i < 4; i++) {
    int idx = tid + i * 256;
    ((float4*)xs)[idx] = x4[(idx >> 4) * 400 + (idx & 15)];
  }
  const float4* w4 = (const float4*)w;
#pragma unroll
  for (int i = 0; i < 4; i++) {
    int idx = tid + i * 256;
    int icq = idx >> 6, oc = idx & 63;
    float4 f = w4[oc * 64 + ich * 16 + icq];
    wsA[(icq * 4 + 0) * 64 + oc] = f.x;
    wsA[(icq * 4 + 1) * 64 + oc] = f.y;
    wsA[(icq * 4 + 2) * 64 + oc] = f.z;
    wsA[(icq * 4 + 3) * 64 + oc] = f.w;
  }
  __syncthreads();

  const int ty = tid >> 4, tx = tid & 15;
  float acc[4][4];
#pragma unroll
  for (int i = 0; i < 4; i++)
#pragma unroll
    for (int j = 0; j < 4; j++) acc[i][j] = 0.f;

#pragma unroll 4
  for (int icl = 0; icl < 64; icl++) {
    float4 a = *(const float4*)&wsA[icl * 64 + ty * 4];
    float4 bb = *(const float4*)&xs[icl * 64 + tx * 4];
    float av[4] = {a.x, a.y, a.z, a.w};
    float bv[4] = {bb.x, bb.y, bb.z, bb.w};
#pragma unroll
    for (int i = 0; i < 4; i++)
#pragma unroll
      for (int j = 0; j < 4; j++) acc[i][j] += av[i] * bv[j];
  }

  float* o = pc + ((size_t)ich * B + b) * CM * HW + t * 64 + tx * 4;
#pragma unroll
  for (int j = 0; j < 4; j++)
    *(float4*)&o[(size_t)(ty * 4 + j) * HW] =
        make_float4(acc[j][0], acc[j][1], acc[j][2], acc[j][3]);
}

// ---------------------------------------------------------------------------
// K2: 3x3 conv 64 -> 100. (unchanged from round 3)
// grid (25 tiles, 4 ocq, 4 icq) = 400 blocks; both batches merged per block.
// ---------------------------------------------------------------------------
__global__ __launch_bounds__(256) void k2_conv3x3(
    const float* __restrict__ pc, const float* __restrict__ w,
    float* __restrict__ encP) {
  const int tile = blockIdx.x, ocq = blockIdx.y, icq = blockIdx.z;
  const int ty5 = tile / 5, tx5 = tile % 5;
  __shared__ __align__(16) float smem[3200 + 16 * 9 * 28];  // 28.9 KB
  float* cs  = smem;
  float* wsb = smem + 3200;
  float* pacc = smem;
  const int tid = threadIdx.x;

  for (int i = tid; i < 3200; i += 256) {
    int bb = i / 1600, r = i - bb * 1600;
    int icl = r / 100, rr = r - icl * 100;
    int yy = rr / 10, xx = rr - yy * 10;
    int gy = ty5 * 8 + yy - 1, gx = tx5 * 8 + xx - 1;
    float v = 0.f;
    if (gy >= 0 && gy < H && gx >= 0 && gx < W) {
      int o = bb * 102400 + (icq * 16 + icl) * HW + gy * W + gx;
      v = pc[o] + pc[204800 + o] + pc[409600 + o] + pc[614400 + o];
    }
    cs[i] = v;
  }
  const float* wb = w + (size_t)(ocq * 25) * 576 + (size_t)(icq * 16) * 9;
  for (int i = tid; i < 3600; i += 256) {
    int ol = i / 144, r = i - ol * 144;
    wsb[r * 28 + ol] = wb[ol * 576 + r];
  }
  __syncthreads();

  const int wv = tid >> 6, lane = tid & 63, py = lane >> 3, px = lane & 7;
  float acc[50];
#pragma unroll
  for (int j = 0; j < 50; j++) acc[j] = 0.f;

#pragma unroll 1
  for (int t = 0; t < 4; t++) {
    const int icl = wv * 4 + t;
    const float* c0 = &cs[icl * 100 + py * 10 + px];
    const float* c1 = c0 + 1600;
    const float* wrow = &wsb[icl * 9 * 28];
#pragma unroll
    for (int dy = 0; dy < 3; dy++) {
#pragma unroll
      for (int dx = 0; dx < 3; dx++) {
        float x0 = c0[dy * 10 + dx];
        float x1 = c1[dy * 10 + dx];
        const float* wp = &wrow[(dy * 3 + dx) * 28];
        float4 w0 = *(const float4*)&wp[0],  w1 = *(const float4*)&wp[4];
        float4 w2 = *(const float4*)&wp[8],  w3 = *(const float4*)&wp[12];
        float4 w4v = *(const float4*)&wp[16], w5 = *(const float4*)&wp[20];
        float w6 = wp[24];
        acc[0]  += x0 * w0.x;  acc[1]  += x0 * w0.y;  acc[2]  += x0 * w0.z;  acc[3]  += x0 * w0.w;
        acc[4]  += x0 * w1.x;  acc[5]  += x0 * w1.y;  acc[6]  += x0 * w1.z;  acc[7]  += x0 * w1.w;
        acc[8]  += x0 * w2.x;  acc[9]  += x0 * w2.y;  acc[10] += x0 * w2.z;  acc[11] += x0 * w2.w;
        acc[12] += x0 * w3.x;  acc[13] += x0 * w3.y;  acc[14] += x0 * w3.z;  acc[15] += x0 * w3.w;
        acc[16] += x0 * w4v.x; acc[17] += x0 * w4v.y; acc[18] += x0 * w4v.z; acc[19] += x0 * w4v.w;
        acc[20] += x0 * w5.x;  acc[21] += x0 * w5.y;  acc[22] += x0 * w5.z;  acc[23] += x0 * w5.w;
        acc[24] += x0 * w6;
        acc[25] += x1 * w0.x;  acc[26] += x1 * w0.y;  acc[27] += x1 * w0.z;  acc[28] += x1 * w0.w;
        acc[29] += x1 * w1.x;  acc[30] += x1 * w1.y;  acc[31] += x1 * w1.z;  acc[32] += x1 * w1.w;
        acc[33] += x1 * w2.x;  acc[34] += x1 * w2.y;  acc[35] += x1 * w2.z;  acc[36] += x1 * w2.w;
        acc[37] += x1 * w3.x;  acc[38] += x1 * w3.y;  acc[39] += x1 * w3.z;  acc[40] += x1 * w3.w;
        acc[41] += x1 * w4v.x; acc[42] += x1 * w4v.y; acc[43] += x1 * w4v.z; acc[44] += x1 * w4v.w;
        acc[45] += x1 * w5.x;  acc[46] += x1 * w5.y;  acc[47] += x1 * w5.z;  acc[48] += x1 * w5.w;
        acc[49] += x1 * w6;
      }
    }
  }

  __syncthreads();
  if (wv == 1 || wv == 3) {
    const int slot = wv >> 1;
#pragma unroll
    for (int j = 0; j < 50; j++) pacc[slot * 3200 + j * 64 + lane] = acc[j];
  }
  __syncthreads();
  if (wv == 0 || wv == 2) {
    const int slot = wv >> 1;
#pragma unroll
    for (int j = 0; j < 50; j++) acc[j] += pacc[slot * 3200 + j * 64 + lane];
  }
  __syncthreads();
  if (wv == 2) {
#pragma unroll
    for (int j = 0; j < 50; j++) pacc[j * 64 + lane] = acc[j];
  }
  __syncthreads();
  if (wv == 0) {
    const int base_px = (ty5 * 8 + py) * W + tx5 * 8 + px;
#pragma unroll
    for (int bb = 0; bb < 2; bb++)
#pragma unroll
      for (int ol = 0; ol < 25; ol++)
        encP[(((size_t)icq * 2 + bb) * CE + ocq * 25 + ol) * HW + base_px] =
            acc[bb * 25 + ol] + pacc[(bb * 25 + ol) * 64 + lane];
  }
}

// ---------------------------------------------------------------------------
// K3 v2: softmax (sums 4 enc partials) + reassembly, TWO source rows/block.
// grid (40 = ib*2 + jh, 4 cq, 2 b) = 320 blocks, block 256 (4 waves).
// Block covers i0 in {2ib, 2ib+1}, output rows hu = 2*i0 + jh (wu in [0,80)),
// 64 channels (cq), one batch. x tile: 6 rows x 24 cols per channel.
// Phase 1 (160 threads): softmax -> wlds[(i0l*20 + j0l)*25 + k][d].
// Phase 2: lane = channel; 9-wide x register cache per (i0l, ki) row.
// LDS 53.1 KB -> 3 blocks/CU, 12 waves/CU.
// ---------------------------------------------------------------------------
__global__ __launch_bounds__(256) void k3_reassemble(
    const float* __restrict__ x, const float* __restrict__ encP,
    float* __restrict__ out) {
  const int ib = blockIdx.x >> 1;      // i0 pair: {2ib, 2ib+1}
  const int jh = blockIdx.x & 1;       // hu parity
  const int cq = blockIdx.y;
  const int b = blockIdx.z;

  __shared__ __align__(16) float wlds[2 * 20 * KK * 4];  // 16 KB
  __shared__ float xsm[64 * 145];                        // 37.1 KB [c][r*24+t]

  const int tid = threadIdx.x;

  // ---- phase 1: softmax for 160 outputs (2 i0 x 20 j0l x 4 d)
  if (tid < 160) {
    const int i0l = tid / 80;
    const int rem = tid - i0l * 80;
    const int j0l = rem >> 2, d = rem & 3;
    const int i0 = 2 * ib + i0l;
    const int off = jh * 2 + (d & 1);          // channel offset within k*4
    const int colw = j0l * 2 + (d >> 1);       // weight spatial col = wu>>1
    const float* ep = encP + (size_t)b * CE * HW + i0 * W + colw;
    float v[KK];
    float m = -1e30f;
#pragma unroll
    for (int k = 0; k < KK; k++) {
      int o = (k * 4 + off) * HW;
      v[k] = ep[o] + ep[320000 + o] + ep[640000 + o] + ep[960000 + o];
      m = fmaxf(m, v[k]);
    }
    float s = 0.f;
#pragma unroll
    for (int k = 0; k < KK; k++) {
      v[k] = expf(v[k] - m);
      s += v[k];
    }
    const float inv = 1.f / s;
#pragma unroll
    for (int k = 0; k < KK; k++)
      wlds[((i0l * 20 + j0l) * KK + k) * 4 + d] = v[k] * inv;
  }

  // ---- stage x tile: 64 c x 6 rows x 24 cols (zero-padded halo)
  const float* xb = x + ((size_t)b * C + cq * 64) * HW;
  for (int i = tid; i < 64 * 144; i += 256) {
    int c = i / 144;
    int rr = i - c * 144;
    int r = rr / 24, t = rr - r * 24;
    int gy = 2 * ib - 2 + r;
    int gx = jh * 20 + t - 2;
    float v = 0.f;
    if (gy >= 0 && gy < H && gx >= 0 && gx < W) v = xb[c * HW + gy * W + gx];
    xsm[c * 145 + r * 24 + t] = v;
  }
  __syncthreads();

  // ---- phase 2
  const int wv = tid >> 6;
  const int lane = tid & 63;
  const float* xrow = &xsm[lane * 145];
  float* obase = out + (((size_t)b * C + cq * 64 + lane) * 6400) + jh * 80;

#pragma unroll 1
  for (int i0l = 0; i0l < 2; i0l++) {
    float a[5][4];
#pragma unroll
    for (int jj = 0; jj < 5; jj++)
#pragma unroll
      for (int d = 0; d < 4; d++) a[jj][d] = 0.f;

#pragma unroll
    for (int ki = 0; ki < 5; ki++) {
      float xv[9];
      const float* xr = &xrow[(i0l + ki) * 24 + wv * 5];
#pragma unroll
      for (int q = 0; q < 9; q++) xv[q] = xr[q];
      const float* wrow = &wlds[((i0l * 20 + wv * 5) * KK + ki * 5) * 4];
#pragma unroll
      for (int jj = 0; jj < 5; jj++) {
#pragma unroll
        for (int kj = 0; kj < 5; kj++) {
          float4 w4 = *(const float4*)&wrow[(jj * KK + kj) * 4];
          float xvv = xv[jj + kj];
          a[jj][0] += xvv * w4.x;
          a[jj][1] += xvv * w4.y;
          a[jj][2] += xvv * w4.z;
          a[jj][3] += xvv * w4.w;
        }
      }
    }
    float* ob = obase + (size_t)(2 * ib + i0l) * 160;   // hu*80 = (2*i0+jh)*80
#pragma unroll
    for (int jj = 0; jj < 5; jj++)
      *(float4*)&ob[(wv * 5 + jj) * 4] =
          make_float4(a[jj][0], a[jj][1], a[jj][2], a[jj][3]);
  }
}

// ---------------------------------------------------------------------------
extern "C" void kernel_launch(void* const* d_in, const int* in_sizes, int n_in,
                              void* d_out, int out_size, void* d_ws, size_t ws_size,
                              hipStream_t stream) {
  const float* x      = (const float*)d_in[0];
  const float* w_comp = (const float*)d_in[1];
  const float* w_enc  = (const float*)d_in[2];
  float* out = (float*)d_out;

  float* pc   = (float*)d_ws;                        // 4*2*64*1600*4  = 3,276,800 B
  float* encP = (float*)((char*)d_ws + 3276800);     // 4*2*100*1600*4 = 5,120,000 B

  k1_conv1x1<<<dim3(25, 4, B), 256, 0, stream>>>(x, w_comp, pc);
  k2_conv3x3<<<dim3(25, 4, 4), 256, 0, stream>>>(pc, w_enc, encP);
  k3_reassemble<<<dim3(40, 4, B), 256, 0, stream>>>(x, encP, out);
}

// Round 5
// 110.575 us; speedup vs baseline: 1.0358x; 1.0358x over previous
//
#include <hip/hip_runtime.h>

#define B   2
#define C   256
#define CM  64     // compressed channels
#define CE  100    // encoder out channels
#define H   40
#define W   40
#define HW  1600
#define KK  25     // K*K

// ---------------------------------------------------------------------------
// K1: 1x1 conv 256 -> 64 as LDS GEMM, K(=x channels) split 4-way over blocks.
// grid (25 px-tiles, 4 K-quarters, 2 b), block 256 = 16 ty(oc) x 16 tx(px),
// thread tile 4 oc x 4 px. Output: fp32 partials pc[ich][b][64][1600].
// (unchanged from round 3)
// ---------------------------------------------------------------------------
__global__ __launch_bounds__(256) void k1_conv1x1(
    const float* __restrict__ x, const float* __restrict__ w,
    float* __restrict__ pc) {
  const int t = blockIdx.x, ich = blockIdx.y, b = blockIdx.z;
  __shared__ __align__(16) float xs[64 * 64];    // 16 KB [icl][px]
  __shared__ __align__(16) float wsA[64 * 64];   // 16 KB [icl][oc] (transposed)
  const int tid = threadIdx.x;

  const float4* x4 = (const float4*)(x + ((size_t)b * C + ich * 64) * HW + t * 64);
#pragma unroll
  for (int i = 0; i < 4; i++) {
    int idx = tid + i * 256;
    ((float4*)xs)[idx] = x4[(idx >> 4) * 400 + (idx & 15)];
  }
  const float4* w4 = (const float4*)w;
#pragma unroll
  for (int i = 0; i < 4; i++) {
    int idx = tid + i * 256;
    int icq = idx >> 6, oc = idx & 63;
    float4 f = w4[oc * 64 + ich * 16 + icq];
    wsA[(icq * 4 + 0) * 64 + oc] = f.x;
    wsA[(icq * 4 + 1) * 64 + oc] = f.y;
    wsA[(icq * 4 + 2) * 64 + oc] = f.z;
    wsA[(icq * 4 + 3) * 64 + oc] = f.w;
  }
  __syncthreads();

  const int ty = tid >> 4, tx = tid & 15;
  float acc[4][4];
#pragma unroll
  for (int i = 0; i < 4; i++)
#pragma unroll
    for (int j = 0; j < 4; j++) acc[i][j] = 0.f;

#pragma unroll 4
  for (int icl = 0; icl < 64; icl++) {
    float4 a = *(const float4*)&wsA[icl * 64 + ty * 4];
    float4 bb = *(const float4*)&xs[icl * 64 + tx * 4];
    float av[4] = {a.x, a.y, a.z, a.w};
    float bv[4] = {bb.x, bb.y, bb.z, bb.w};
#pragma unroll
    for (int i = 0; i < 4; i++)
#pragma unroll
      for (int j = 0; j < 4; j++) acc[i][j] += av[i] * bv[j];
  }

  float* o = pc + ((size_t)ich * B + b) * CM * HW + t * 64 + tx * 4;
#pragma unroll
  for (int j = 0; j < 4; j++)
    *(float4*)&o[(size_t)(ty * 4 + j) * HW] =
        make_float4(acc[j][0], acc[j][1], acc[j][2], acc[j][3]);
}

// ---------------------------------------------------------------------------
// K2: 3x3 conv 64 -> 100. (unchanged from round 3)
// grid (25 tiles, 4 ocq, 4 icq) = 400 blocks; both batches merged per block.
// ---------------------------------------------------------------------------
__global__ __launch_bounds__(256) void k2_conv3x3(
    const float* __restrict__ pc, const float* __restrict__ w,
    float* __restrict__ encP) {
  const int tile = blockIdx.x, ocq = blockIdx.y, icq = blockIdx.z;
  const int ty5 = tile / 5, tx5 = tile % 5;
  __shared__ __align__(16) float smem[3200 + 16 * 9 * 28];  // 28.9 KB
  float* cs  = smem;
  float* wsb = smem + 3200;
  float* pacc = smem;
  const int tid = threadIdx.x;

  for (int i = tid; i < 3200; i += 256) {
    int bb = i / 1600, r = i - bb * 1600;
    int icl = r / 100, rr = r - icl * 100;
    int yy = rr / 10, xx = rr - yy * 10;
    int gy = ty5 * 8 + yy - 1, gx = tx5 * 8 + xx - 1;
    float v = 0.f;
    if (gy >= 0 && gy < H && gx >= 0 && gx < W) {
      int o = bb * 102400 + (icq * 16 + icl) * HW + gy * W + gx;
      v = pc[o] + pc[204800 + o] + pc[409600 + o] + pc[614400 + o];
    }
    cs[i] = v;
  }
  const float* wb = w + (size_t)(ocq * 25) * 576 + (size_t)(icq * 16) * 9;
  for (int i = tid; i < 3600; i += 256) {
    int ol = i / 144, r = i - ol * 144;
    wsb[r * 28 + ol] = wb[ol * 576 + r];
  }
  __syncthreads();

  const int wv = tid >> 6, lane = tid & 63, py = lane >> 3, px = lane & 7;
  float acc[50];
#pragma unroll
  for (int j = 0; j < 50; j++) acc[j] = 0.f;

#pragma unroll 1
  for (int t = 0; t < 4; t++) {
    const int icl = wv * 4 + t;
    const float* c0 = &cs[icl * 100 + py * 10 + px];
    const float* c1 = c0 + 1600;
    const float* wrow = &wsb[icl * 9 * 28];
#pragma unroll
    for (int dy = 0; dy < 3; dy++) {
#pragma unroll
      for (int dx = 0; dx < 3; dx++) {
        float x0 = c0[dy * 10 + dx];
        float x1 = c1[dy * 10 + dx];
        const float* wp = &wrow[(dy * 3 + dx) * 28];
        float4 w0 = *(const float4*)&wp[0],  w1 = *(const float4*)&wp[4];
        float4 w2 = *(const float4*)&wp[8],  w3 = *(const float4*)&wp[12];
        float4 w4v = *(const float4*)&wp[16], w5 = *(const float4*)&wp[20];
        float w6 = wp[24];
        acc[0]  += x0 * w0.x;  acc[1]  += x0 * w0.y;  acc[2]  += x0 * w0.z;  acc[3]  += x0 * w0.w;
        acc[4]  += x0 * w1.x;  acc[5]  += x0 * w1.y;  acc[6]  += x0 * w1.z;  acc[7]  += x0 * w1.w;
        acc[8]  += x0 * w2.x;  acc[9]  += x0 * w2.y;  acc[10] += x0 * w2.z;  acc[11] += x0 * w2.w;
        acc[12] += x0 * w3.x;  acc[13] += x0 * w3.y;  acc[14] += x0 * w3.z;  acc[15] += x0 * w3.w;
        acc[16] += x0 * w4v.x; acc[17] += x0 * w4v.y; acc[18] += x0 * w4v.z; acc[19] += x0 * w4v.w;
        acc[20] += x0 * w5.x;  acc[21] += x0 * w5.y;  acc[22] += x0 * w5.z;  acc[23] += x0 * w5.w;
        acc[24] += x0 * w6;
        acc[25] += x1 * w0.x;  acc[26] += x1 * w0.y;  acc[27] += x1 * w0.z;  acc[28] += x1 * w0.w;
        acc[29] += x1 * w1.x;  acc[30] += x1 * w1.y;  acc[31] += x1 * w1.z;  acc[32] += x1 * w1.w;
        acc[33] += x1 * w2.x;  acc[34] += x1 * w2.y;  acc[35] += x1 * w2.z;  acc[36] += x1 * w2.w;
        acc[37] += x1 * w3.x;  acc[38] += x1 * w3.y;  acc[39] += x1 * w3.z;  acc[40] += x1 * w3.w;
        acc[41] += x1 * w4v.x; acc[42] += x1 * w4v.y; acc[43] += x1 * w4v.z; acc[44] += x1 * w4v.w;
        acc[45] += x1 * w5.x;  acc[46] += x1 * w5.y;  acc[47] += x1 * w5.z;  acc[48] += x1 * w5.w;
        acc[49] += x1 * w6;
      }
    }
  }

  __syncthreads();
  if (wv == 1 || wv == 3) {
    const int slot = wv >> 1;
#pragma unroll
    for (int j = 0; j < 50; j++) pacc[slot * 3200 + j * 64 + lane] = acc[j];
  }
  __syncthreads();
  if (wv == 0 || wv == 2) {
    const int slot = wv >> 1;
#pragma unroll
    for (int j = 0; j < 50; j++) acc[j] += pacc[slot * 3200 + j * 64 + lane];
  }
  __syncthreads();
  if (wv == 2) {
#pragma unroll
    for (int j = 0; j < 50; j++) pacc[j * 64 + lane] = acc[j];
  }
  __syncthreads();
  if (wv == 0) {
    const int base_px = (ty5 * 8 + py) * W + tx5 * 8 + px;
#pragma unroll
    for (int bb = 0; bb < 2; bb++)
#pragma unroll
      for (int ol = 0; ol < 25; ol++)
        encP[(((size_t)icq * 2 + bb) * CE + ocq * 25 + ol) * HW + base_px] =
            acc[bb * 25 + ol] + pacc[(bb * 25 + ol) * 64 + lane];
  }
}

// ---------------------------------------------------------------------------
// K3 v3: R3 structure (640 blocks, 39 KB LDS, one source row / block) with
// the 9-wide x register cache from R4's phase 2.
// grid (80 = i0*2 + jh, 4 cq, 2 b), block 256 (4 waves).
// ---------------------------------------------------------------------------
__global__ __launch_bounds__(256) void k3_reassemble(
    const float* __restrict__ x, const float* __restrict__ encP,
    float* __restrict__ out) {
  const int i0 = blockIdx.x >> 1;
  const int jh = blockIdx.x & 1;
  const int cq = blockIdx.y;
  const int b = blockIdx.z;

  __shared__ __align__(16) float wlds[20 * KK * 4];  // 8 KB  [j0loc][k][d]
  __shared__ float xsm[64 * 121];                    // 31 KB [c][r*24 + t]

  const int tid = threadIdx.x;

  // ---- phase 1: softmax for this (i0, jh) half-row: 20 j0 x 4 d = 80 elems
  if (tid < 80) {
    const int e = jh * 80 + tid;
    const int j0 = e >> 2, d = e & 3;
    const int off = ((e >= 80) ? 2 : 0) + (e & 1);
    const int col = ((e >= 80) ? (j0 - 20) : j0) * 2 + (d >> 1);
    const float* ep = encP + (size_t)b * CE * HW + i0 * W + col;
    float v[KK];
    float m = -1e30f;
#pragma unroll
    for (int k = 0; k < KK; k++) {
      int o = (k * 4 + off) * HW;
      v[k] = ep[o] + ep[320000 + o] + ep[640000 + o] + ep[960000 + o];
      m = fmaxf(m, v[k]);
    }
    float s = 0.f;
#pragma unroll
    for (int k = 0; k < KK; k++) {
      v[k] = expf(v[k] - m);
      s += v[k];
    }
    const float inv = 1.f / s;
    const int j0l = j0 - jh * 20;
#pragma unroll
    for (int k = 0; k < KK; k++) wlds[(j0l * KK + k) * 4 + d] = v[k] * inv;
  }

  // ---- stage x tile: 64 c x 5 rows x 24 cols (zero-padded halo)
  const float* xb = x + ((size_t)b * C + cq * 64) * HW;
  for (int i = tid; i < 64 * 120; i += 256) {
    int c = i / 120;
    int rr = i % 120;
    int r = rr / 24, t = rr % 24;
    int gy = i0 - 2 + r;
    int gx = jh * 20 + t - 2;
    float v = 0.f;
    if (gy >= 0 && gy < H && gx >= 0 && gx < W) v = xb[c * HW + gy * W + gx];
    xsm[c * 121 + r * 24 + t] = v;
  }
  __syncthreads();

  // ---- phase 2: lane = channel, wave owns 5 consecutive j0l.
  const int wv = tid >> 6;
  const int lane = tid & 63;
  const int j0b = wv * 5;                       // local j0 base for this wave
  const float* xrow = &xsm[lane * 121];
  float* ob = out + (((size_t)b * C + cq * 64 + lane) * 6400) + i0 * 160;

  float a[5][4];
#pragma unroll
  for (int jj = 0; jj < 5; jj++)
#pragma unroll
    for (int d = 0; d < 4; d++) a[jj][d] = 0.f;

#pragma unroll
  for (int ki = 0; ki < 5; ki++) {
    float xv[9];
    const float* xr = &xrow[ki * 24 + j0b];
#pragma unroll
    for (int q = 0; q < 9; q++) xv[q] = xr[q];
    const float* wrow = &wlds[(j0b * KK + ki * 5) * 4];
#pragma unroll
    for (int jj = 0; jj < 5; jj++) {
#pragma unroll
      for (int kj = 0; kj < 5; kj++) {
        float4 w4 = *(const float4*)&wrow[(jj * KK + kj) * 4];
        float xvv = xv[jj + kj];
        a[jj][0] += xvv * w4.x;
        a[jj][1] += xvv * w4.y;
        a[jj][2] += xvv * w4.z;
        a[jj][3] += xvv * w4.w;
      }
    }
  }
#pragma unroll
  for (int jj = 0; jj < 5; jj++)
    *(float4*)&ob[(jh * 20 + j0b + jj) * 4] =
        make_float4(a[jj][0], a[jj][1], a[jj][2], a[jj][3]);
}

// ---------------------------------------------------------------------------
extern "C" void kernel_launch(void* const* d_in, const int* in_sizes, int n_in,
                              void* d_out, int out_size, void* d_ws, size_t ws_size,
                              hipStream_t stream) {
  const float* x      = (const float*)d_in[0];
  const float* w_comp = (const float*)d_in[1];
  const float* w_enc  = (const float*)d_in[2];
  float* out = (float*)d_out;

  float* pc   = (float*)d_ws;                        // 4*2*64*1600*4  = 3,276,800 B
  float* encP = (float*)((char*)d_ws + 3276800);     // 4*2*100*1600*4 = 5,120,000 B

  k1_conv1x1<<<dim3(25, 4, B), 256, 0, stream>>>(x, w_comp, pc);
  k2_conv3x3<<<dim3(25, 4, 4), 256, 0, stream>>>(pc, w_enc, encP);
  k3_reassemble<<<dim3(80, 4, B), 256, 0, stream>>>(x, encP, out);
}